// Round 7
// baseline (541.564 us; speedup 1.0000x reference)
//
#include <hip/hip_runtime.h>
#include <stdint.h>
#include <math.h>

#define B_   32
#define S_   512
#define H_   256
#define M_   (B_*S_)     // 16384 tokens
#define KBIG 1024        // [hb|ha|hh|wv]
#define NB   1792        // 7*H
#define NB2  2048        // 7*H gates + 256 fgih rows (zero-padded K)
#define C_   5

typedef __bf16 bf16;
typedef __bf16 bf16x4 __attribute__((ext_vector_type(4)));
typedef __bf16 bf16x8 __attribute__((ext_vector_type(8)));
typedef float  floatx4 __attribute__((ext_vector_type(4)));

__device__ __forceinline__ float sigm(float x){ return 1.f/(1.f+expf(-x)); }

// async global->LDS, 16B per lane; LDS dest must be wave-uniform base + lane*16
__device__ __forceinline__ void gl16(const bf16* g, bf16* l){
    __builtin_amdgcn_global_load_lds(
        (const __attribute__((address_space(1))) unsigned int*)g,
        (__attribute__((address_space(3))) unsigned int*)l, 16, 0, 0);
}

// ---------- WT2: rows 0..1791 = [W_lr|W_c|W_x]; rows 1792..2047 = [0|Wfgi_h|0] ----------
__global__ void wcomb_k(const float* __restrict__ Wlr, const float* __restrict__ Wc,
                        const float* __restrict__ Wx, const float* __restrict__ Wfgi,
                        bf16* __restrict__ WT){
    int n = blockIdx.x;           // 0..2047
    int k4 = threadIdx.x * 4;     // 0..1020
    float4 v;
    if (n < NB){
        int g = n >> 8, h = n & 255;
        const float* src;
        if (k4 < 512)      src = Wlr + ((size_t)(g*256 + h))*512 + k4;
        else if (k4 < 768) src = Wc  + ((size_t)(g*256 + h))*256 + (k4 - 512);
        else               src = Wx  + ((size_t)(g*256 + h))*256 + (k4 - 768);
        v = *(const float4*)src;
    } else {
        int h = n - NB;
        if (k4 >= 512 && k4 < 768) v = *(const float4*)(Wfgi + (size_t)h*H_ + (k4 - 512));
        else { v.x=0.f; v.y=0.f; v.z=0.f; v.w=0.f; }
    }
    bf16 o[4] = {(bf16)v.x,(bf16)v.y,(bf16)v.z,(bf16)v.w};
    *(uint2*)&WT[(size_t)n*KBIG + k4] = *(uint2*)o;
}

// ---------- X[m, 768+h] = (bf16)embed[idx[m],h]  (seg-3 static across layers) ----------
__global__ void gather_k(const int* __restrict__ idx, const float* __restrict__ embed,
                         bf16* __restrict__ X){
    int i4 = (blockIdx.x*256 + threadIdx.x)*4;
    int m = i4 >> 8, h = i4 & 255;
    float4 v = *(const float4*)(embed + (size_t)idx[m]*H_ + h);
    bf16 o[4] = {(bf16)v.x,(bf16)v.y,(bf16)v.z,(bf16)v.w};
    *(uint2*)(X + (size_t)m*KBIG + 768 + h) = *(uint2*)o;
}

// ---------- two-stage mean over S ----------
__global__ void mean1_k(const float* __restrict__ x, float* __restrict__ part){
    int b = blockIdx.x, c = blockIdx.y, h = threadIdx.x;   // grid (B_,16)
    const float* p = x + ((size_t)b*S_ + c*32)*H_ + h;
    float s = 0.f;
    #pragma unroll 8
    for (int t=0;t<32;t++) s += p[(size_t)t*H_];
    part[((size_t)b*16 + c)*H_ + h] = s;
}
__global__ void mean2_k(const float* __restrict__ part, float* __restrict__ out){
    int b = blockIdx.x, h = threadIdx.x;
    float s = 0.f;
    #pragma unroll
    for (int c=0;c<16;c++) s += part[((size_t)b*16 + c)*H_ + h];
    out[b*H_ + h] = s * (1.f/512.f);
}

// ---------- X segs: 0=hb, 1=ha, 2=hh(bf16). Layer0: 192 thr (segs 0-2, seg2 from hin);
// ---------- layer1: 128 thr (segs 0-1; seg2 was written by gates_k). seg3 static. ----------
__global__ void buildx_k(const float* __restrict__ hh, bf16* __restrict__ X){
    int m = blockIdx.x, tid = threadIdx.x;
    int seg = tid >> 6, li = tid & 63;          // seg uniform per wave
    int s = m & (S_-1);
    int h0 = li*4;
    size_t base = (size_t)m*H_ + h0;
    bf16* xr = X + (size_t)m*KBIG + seg*H_ + h0;
    const float4 z = {0.f,0.f,0.f,0.f};
    float4 v;
    if (seg == 0){
        float4 a = (s>=1) ? *(const float4*)&hh[base - H_]   : z;
        float4 b = (s>=2) ? *(const float4*)&hh[base - 2*H_] : z;
        v.x=a.x+b.x; v.y=a.y+b.y; v.z=a.z+b.z; v.w=a.w+b.w;
    } else if (seg == 1){
        float4 a = (s<=S_-2) ? *(const float4*)&hh[base + H_]   : z;
        float4 b = (s<=S_-3) ? *(const float4*)&hh[base + 2*H_] : z;
        v.x=a.x+b.x; v.y=a.y+b.y; v.z=a.z+b.z; v.w=a.w+b.w;
    } else {
        v = *(const float4*)&hh[base];
    }
    bf16 o[4] = {(bf16)v.x,(bf16)v.y,(bf16)v.z,(bf16)v.w};
    *(uint2*)xr = *(uint2*)o;
}

// ---------- 5 small matvecs: res[b*5+j][h] ----------
__global__ void mv5_k(const float* __restrict__ sv, const float* __restrict__ avg,
    const float* __restrict__ Wfg_g, const float* __restrict__ Wfg_h,
    const float* __restrict__ Wog_g, const float* __restrict__ Wog_h,
    const float* __restrict__ Wfgi_g, float* __restrict__ res){
    int j = blockIdx.x, b = blockIdx.y, h = threadIdx.x;   // grid (5,B_)
    const float* vec = (j==1 || j==3) ? avg + b*H_ : sv + b*H_;
    const float* W   = (j==0)?Wfg_g:(j==1)?Wfg_h:(j==2)?Wog_g:(j==3)?Wog_h:Wfgi_g;
    __shared__ float v[H_];
    v[h] = vec[h]; __syncthreads();
    const float* w = W + (size_t)h*H_;
    float d = 0.f;
    for (int k=0;k<H_;k++) d += v[k]*w[k];
    res[((size_t)b*5 + j)*H_ + h] = d;
}
__global__ void comb_k(const float* __restrict__ res, const float* __restrict__ b_fg,
                       const float* __restrict__ gbias, const float* __restrict__ b_fgi,
                       float* __restrict__ fhg, float* __restrict__ ogg,
                       float* __restrict__ svg){
    int b = blockIdx.x, h = threadIdx.x;
    const float* r = res + (size_t)b*5*H_;
    fhg[b*H_+h] = sigm(r[h] + r[H_+h] + b_fg[h]);
    ogg[b*H_+h] = sigm(r[2*H_+h] + r[3*H_+h] + gbias[5*H_+h]);  // gate_bias[5] per ref
    svg[b*H_+h] = r[4*H_+h] + b_fgi[h];
}

// ---------- 256x256 MFMA GEMM, BK=32 RING-4 deep pipeline ----------
// R7: prefetch distance was the wall (all 2-buffer variants cap lookahead at 1 K-tile
// ~600cyc < ~900cyc load latency). Ring of 4 tile-slots (32KB each, 128KB total):
// at iter kt stage tile kt+3 (4 gloads), vmcnt(12) -> tile kt landed (3 tiles = 12 loads
// stay in flight = ~1800cyc coverage), barrier, 12 ds_read_b128 + 32 independent MFMA,
// lgkmcnt(0), barrier (WAR: next iter overwrites tile kt-... slot of kt+4's buffer).
// BK=32 (64B rows) is naturally bank-balanced -> NO swizzle, linear staging and reads.
__global__ __launch_bounds__(512, 2)
void mgemm256_k(const bf16* __restrict__ A, const bf16* __restrict__ BT,
                bf16* __restrict__ C, int Kdim, int lda, int ldb, int ldc, int nbx){
    __shared__ alignas(16) bf16 lsA[4][256*32];
    __shared__ alignas(16) bf16 lsB[4][256*32];
    const int tid  = threadIdx.x;
    const int lane = tid & 63;
    const int wave = tid >> 6;
    const int wm = wave >> 2;          // 0..1  (m half: rows wm*128..+127)
    const int wn = wave & 3;           // 0..3  (n quarter: cols wn*64..+63)
    const int lrow = lane & 15, quad = lane >> 4;

    // XCD-chunked swizzle (gridDim.x % 8 == 0 -> bijective)
    const int cpx = gridDim.x >> 3;
    const int w   = (blockIdx.x & 7)*cpx + (blockIdx.x >> 3);
    const int mb  = w / nbx, nb = w - mb*nbx;
    const int m0 = mb * 256, n0 = nb * 256;

    // staging: round r covers rows r*128 + (tid>>2), 8 cols (16B) at slot tid&3; linear.
    const int srow = tid >> 2;                  // 0..127
    const int scol = (tid & 3) * 8;             // 0,8,16,24
    const bf16* Ab = A  + (size_t)(m0 + srow)*lda + scol;
    const bf16* Bb = BT + (size_t)(n0 + srow)*ldb + scol;
    const int NT = Kdim >> 5;                   // BK=32 (NT >= 4)

    floatx4 zero = {0.f,0.f,0.f,0.f};
    floatx4 acc[8][4];
    #pragma unroll
    for (int i=0;i<8;i++)
        #pragma unroll
        for (int j=0;j<4;j++) acc[i][j] = zero;
    bf16x8 af[8], bfr[4];

#define SA_(bu,r,kt) gl16(Ab + (size_t)(r)*128*lda + (size_t)(kt)*32, &lsA[bu][(r)*4096 + tid*8])
#define SB_(bu,r,kt) gl16(Bb + (size_t)(r)*128*ldb + (size_t)(kt)*32, &lsB[bu][(r)*4096 + tid*8])
#define RA_(bu,mi) (*(const bf16x8*)&lsA[bu][(wm*128 + (mi)*16 + lrow)*32 + quad*8])
#define RB_(bu,ni) (*(const bf16x8*)&lsB[bu][(wn*64  + (ni)*16 + lrow)*32 + quad*8])

    // prologue: stage tiles 0,1,2 into slots 0,1,2 (12 loads in flight)
    #pragma unroll
    for (int t=0; t<3; ++t){ SA_(t,0,t); SA_(t,1,t); SB_(t,0,t); SB_(t,1,t); }

    for (int kt = 0; kt < NT; ++kt){
        const int cur = kt & 3;
        const int pf  = kt + 3;
        if (pf < NT){
            const int pb = pf & 3;
            SA_(pb,0,pf); SA_(pb,1,pf); SB_(pb,0,pf); SB_(pb,1,pf);
        }
        const int rem = NT - 1 - kt;            // tiles younger than kt still in flight
        if (rem >= 3)      asm volatile("s_waitcnt vmcnt(12)" ::: "memory");
        else if (rem == 2) asm volatile("s_waitcnt vmcnt(8)"  ::: "memory");
        else if (rem == 1) asm volatile("s_waitcnt vmcnt(4)"  ::: "memory");
        else               asm volatile("s_waitcnt vmcnt(0)"  ::: "memory");
        __builtin_amdgcn_s_barrier();           // all waves' tile-kt stages landed

        #pragma unroll
        for (int mi=0;mi<8;mi++) af[mi]  = RA_(cur,mi);
        #pragma unroll
        for (int ni=0;ni<4;ni++) bfr[ni] = RB_(cur,ni);
        __builtin_amdgcn_s_setprio(1);
        #pragma unroll
        for (int mi=0;mi<8;mi++)
            #pragma unroll
            for (int ni=0;ni<4;ni++)
                acc[mi][ni] = __builtin_amdgcn_mfma_f32_16x16x32_bf16(af[mi], bfr[ni], acc[mi][ni], 0, 0, 0);
        __builtin_amdgcn_s_setprio(0);

        asm volatile("s_waitcnt lgkmcnt(0)" ::: "memory");  // my reads of slot cur done
        __builtin_amdgcn_s_barrier();                       // all waves done (WAR for slot reuse)
    }
#undef SA_
#undef SB_
#undef RA_
#undef RB_

    #pragma unroll
    for (int mi=0;mi<8;mi++)
        #pragma unroll
        for (int ni=0;ni<4;ni++){
            int row = m0 + wm*128 + mi*16 + quad*4;
            int col = n0 + wn*64  + ni*16 + lrow;
            #pragma unroll
            for (int r=0;r<4;r++)
                C[(size_t)(row+r)*ldc + col] = (bf16)acc[mi][ni][r];
        }
}

// ---------- fused score+partial: wave per token; h remapped to lane*4+j for vector loads ----------
__global__ void scorep_k(const bf16* __restrict__ fgih, const float* __restrict__ svg,
                         const float* __restrict__ cs, float* __restrict__ part, int ldf){
    int chunk = blockIdx.x, b = blockIdx.y;                 // grid (32,B_)
    int tid = threadIdx.x, wave = tid >> 6, lane = tid & 63;
    __shared__ float acc4[4][256];
    int h0 = lane*4;
    float4 swv = *(const float4*)&svg[b*H_ + h0];
    float sw[4] = {swv.x, swv.y, swv.z, swv.w};
    float acc[4] = {0.f,0.f,0.f,0.f};
    for (int t=wave; t<16; t+=4){
        int m = b*S_ + chunk*16 + t;
        bf16x4 fv = *(const bf16x4*)&fgih[(size_t)m*ldf + h0];
        float e[4], loc = 0.f;
        #pragma unroll
        for (int j=0;j<4;j++){ e[j] = expf(sigm(sw[j] + (float)fv[j])); loc += e[j]; }
        #pragma unroll
        for (int off=32; off; off>>=1) loc += __shfl_xor(loc, off, 64);
        float inv = 1.f/loc;
        float4 cv = *(const float4*)&cs[(size_t)m*H_ + h0];
        acc[0] += e[0]*inv*cv.x; acc[1] += e[1]*inv*cv.y;
        acc[2] += e[2]*inv*cv.z; acc[3] += e[3]*inv*cv.w;
    }
    #pragma unroll
    for (int j=0;j<4;j++) acc4[wave][h0+j] = acc[j];
    __syncthreads();
    part[((size_t)b*32 + chunk)*H_ + tid] =
        acc4[0][tid] + acc4[1][tid] + acc4[2][tid] + acc4[3][tid];
}

// ---------- new_scs / new_sv (sums 32 partials) ----------
__global__ void newscs_k(const float* __restrict__ part, const float* __restrict__ fhg,
                         const float* __restrict__ ogg, const float* __restrict__ scs_in,
                         float* __restrict__ scs_out, float* __restrict__ sv_out){
    int b = blockIdx.x, h = threadIdx.x;
    __shared__ float r[256];
    float dot = 0.f;
    #pragma unroll 8
    for (int c=0;c<32;c++) dot += part[((size_t)b*32+c)*H_ + h];
    float e = expf(fhg[b*H_+h]);
    r[h] = e; __syncthreads();
    for (int off=128; off; off>>=1){ if (h<off) r[h] += r[h+off]; __syncthreads(); }
    float ns = (e / r[0]) * scs_in[b*H_+h] + dot;
    scs_out[b*H_+h] = ns;
    sv_out[b*H_+h]  = ogg[b*H_+h] * tanhf(ns);
}

// ---------- gt[b, g*256+h] = sum_k new_sv[b,k]*W_g[g,h,k] + gate_bias[g,h] ----------
__global__ void gterm_k(const float* __restrict__ svn, const float* __restrict__ Wg,
                        const float* __restrict__ gbias, float* __restrict__ gt){
    int g = blockIdx.x, b = blockIdx.y, h = threadIdx.x;
    __shared__ float s[H_];
    s[h] = svn[b*H_+h]; __syncthreads();
    const float* w = Wg + ((size_t)g*H_ + h)*H_;
    float d = 0.f;
    for (int k=0;k<H_;k++) d += s[k]*w[k];
    gt[(size_t)b*NB + g*H_ + h] = d + gbias[g*H_+h];
}

// ---------- joint softmax over 5H + state update; writes next layer's X seg-2 (bf16 hh) ----------
__global__ void gates_k(const bf16* __restrict__ pre, const float* __restrict__ gt,
                        const float* __restrict__ cs_in, const float* __restrict__ scs_in,
                        float* __restrict__ hh_out, float* __restrict__ cs_out,
                        bf16* __restrict__ Xn, int ldp){
    int tid = threadIdx.x, wave = tid >> 6, lane = tid & 63;
    int m = blockIdx.x*4 + wave;                             // grid M_/4
    int b = m >> 9, s = m & (S_-1);
    const bf16* row = pre + (size_t)m*ldp;
    int h0 = lane*4;
    float pv[7][4];
    #pragma unroll
    for (int g=0; g<7; ++g){
        bf16x4 t = *(const bf16x4*)&row[g*H_ + h0];
        float4 gq = *(const float4*)&gt[(size_t)b*NB + g*H_ + h0];
        pv[g][0] = (float)t[0] + gq.x;
        pv[g][1] = (float)t[1] + gq.y;
        pv[g][2] = (float)t[2] + gq.z;
        pv[g][3] = (float)t[3] + gq.w;
    }
    float ex[5][4], og[4], u[4];
    float loc = 0.f;
    #pragma unroll
    for (int g=0; g<5; ++g)
        #pragma unroll
        for (int j=0;j<4;j++){ float e = expf(sigm(pv[g][j])); ex[g][j] = e; loc += e; }
    #pragma unroll
    for (int j=0;j<4;j++){ og[j] = sigm(pv[5][j]); u[j] = tanhf(pv[6][j]); }
    #pragma unroll
    for (int off=32; off; off>>=1) loc += __shfl_xor(loc, off, 64);
    float inv = 1.f / loc;

    size_t i0 = (size_t)m*H_ + h0;
    const float4 z = {0.f,0.f,0.f,0.f};
    float4 c0  = *(const float4*)&cs_in[i0];
    float4 cm1 = (s>=1)    ? *(const float4*)&cs_in[i0 - H_]   : z;
    float4 cm2 = (s>=2)    ? *(const float4*)&cs_in[i0 - 2*H_] : z;
    float4 cp1 = (s<=S_-2) ? *(const float4*)&cs_in[i0 + H_]   : z;
    float4 cp2 = (s<=S_-3) ? *(const float4*)&cs_in[i0 + 2*H_] : z;
    float4 sc  = *(const float4*)&scs_in[(size_t)b*H_ + h0];
    float4 nc4, nh4;
    #pragma unroll
    for (int j=0;j<4;j++){
        float cb = ((const float*)&cm1)[j] + ((const float*)&cm2)[j];
        float ca = ((const float*)&cp1)[j] + ((const float*)&cp2)[j];
        // gate order i,l,r,f,s: new_cs = l*cb + f*cs + r*ca + s*scs + i*u
        float nc = ex[1][j]*inv*cb + ex[3][j]*inv*((const float*)&c0)[j] + ex[2][j]*inv*ca
                 + ex[4][j]*inv*((const float*)&sc)[j] + ex[0][j]*inv*u[j];
        ((float*)&nc4)[j] = nc;
        ((float*)&nh4)[j] = og[j] * tanhf(nc);
    }
    *(float4*)&cs_out[i0] = nc4;
    *(float4*)&hh_out[i0] = nh4;
    if (Xn){
        bf16 o[4] = {(bf16)((float*)&nh4)[0], (bf16)((float*)&nh4)[1],
                     (bf16)((float*)&nh4)[2], (bf16)((float*)&nh4)[3]};
        *(uint2*)&Xn[(size_t)m*KBIG + 512 + h0] = *(uint2*)o;
    }
}

// ---------- output head (float32 out) ----------
__global__ void head_k(const float* __restrict__ avgh, const float* __restrict__ sv,
                       const float* __restrict__ W1, const float* __restrict__ b1,
                       const float* __restrict__ Wout, const float* __restrict__ bout,
                       float* __restrict__ out){
    int b = blockIdx.x, t = threadIdx.x;
    __shared__ float conc[H_];
    __shared__ float fc[8];
    const float* wr = W1 + (size_t)t*512;
    float d = b1[t];
    for (int k=0;k<H_;k++) d += avgh[b*H_+k]*wr[k];
    for (int k=0;k<H_;k++) d += sv[b*H_+k]*wr[256+k];
    conc[t] = d;
    __syncthreads();
    if (t < C_){
        const float* wo = Wout + (size_t)t*H_;
        float s = bout[t];
        for (int i=0;i<H_;i++) s += conc[i]*wo[i];
        fc[t] = s;
    }
    __syncthreads();
    if (t == 0){
        float mx = fc[0];
        for (int c=1;c<C_;c++) mx = fmaxf(mx, fc[c]);
        float se = 0.f;
        for (int c=0;c<C_;c++) se += expf(fc[c]-mx);
        float lse = mx + logf(se);
        for (int c=0;c<C_;c++) out[b*C_+c] = fc[c]-lse;
    }
    out[B_*C_ + b*H_ + t] = sv[b*H_+t];
}

// ---------------- host ----------------
extern "C" void kernel_launch(void* const* d_in, const int* in_sizes, int n_in,
                              void* d_out, int out_size, void* d_ws, size_t ws_size,
                              hipStream_t stream){
    const int*   idx    = (const int*)d_in[0];
    const float* hh0    = (const float*)d_in[2];
    const float* cs0    = (const float*)d_in[3];
    const float* embed  = (const float*)d_in[4];
    const float* Wlr    = (const float*)d_in[5];
    const float* Wc     = (const float*)d_in[6];
    const float* Wx     = (const float*)d_in[7];
    const float* Wg     = (const float*)d_in[8];
    const float* gbias  = (const float*)d_in[9];
    const float* Wfg_g  = (const float*)d_in[10];
    const float* Wfg_h  = (const float*)d_in[11];
    const float* Wfgi_g = (const float*)d_in[12];
    const float* Wfgi_h = (const float*)d_in[13];
    const float* Wog_g  = (const float*)d_in[14];
    const float* Wog_h  = (const float*)d_in[15];
    const float* b_fg   = (const float*)d_in[16];
    const float* b_fgi  = (const float*)d_in[17];
    const float* W1     = (const float*)d_in[18];
    const float* b1     = (const float*)d_in[19];
    const float* Wout   = (const float*)d_in[20];
    const float* bout   = (const float*)d_in[21];

    uint8_t* p = (uint8_t*)d_ws;
    auto alloc = [&](size_t bytes)->void*{ void* r=(void*)p; p += (bytes + 255) & ~(size_t)255; return r; };
    bf16*  WT    = (bf16*)alloc((size_t)NB2*KBIG*2);   //  4.2 MB
    bf16*  X     = (bf16*)alloc((size_t)M_*KBIG*2);    // 33.6 MB
    bf16*  pre   = (bf16*)alloc((size_t)M_*NB2*2);     // 67.1 MB  (cols 1792.. = fgih)
    float* hhA = (float*)alloc((size_t)M_*H_*4);
    float* csA = (float*)alloc((size_t)M_*H_*4);
    float* hhB = (float*)alloc((size_t)M_*H_*4);
    float* csB = (float*)alloc((size_t)M_*H_*4);
    float* mpart= (float*)alloc((size_t)B_*16*H_*4);
    float* part = (float*)alloc((size_t)B_*32*H_*4);
    float* res5 = (float*)alloc((size_t)B_*5*H_*4);
    float* avgh = (float*)alloc(B_*H_*4);
    float* fhg  = (float*)alloc(B_*H_*4);
    float* ogg  = (float*)alloc(B_*H_*4);
    float* svg  = (float*)alloc(B_*H_*4);
    float* svP0 = (float*)alloc(B_*H_*4);
    float* svP1 = (float*)alloc(B_*H_*4);
    float* scP0 = (float*)alloc(B_*H_*4);
    float* scP1 = (float*)alloc(B_*H_*4);
    float* gt   = (float*)alloc((size_t)B_*NB*4);

    wcomb_k <<<NB2,         256, 0, stream>>>(Wlr, Wc, Wx, Wfgi_h, WT);
    gather_k<<<(M_*H_)/1024,256, 0, stream>>>(idx, embed, X);
    mean1_k <<<dim3(B_,16), 256, 0, stream>>>(hh0, mpart);
    mean2_k <<<B_,          256, 0, stream>>>(mpart, svP0);   // sv0 == avg_hh(layer0)
    mean1_k <<<dim3(B_,16), 256, 0, stream>>>(cs0, mpart);
    mean2_k <<<B_,          256, 0, stream>>>(mpart, scP0);

    const float *hin = hh0, *cin = cs0;
    float *hout = hhA, *cout = csA;
    float *svin = svP0, *scin = scP0, *svout = svP1, *scout = scP1;

    for (int l=0; l<2; ++l){
        const float* avgp;
        if (l == 0){
            avgp = svin;            // mean(hh0) == initial sv
        } else {
            mean1_k<<<dim3(B_,16), 256, 0, stream>>>(hin, mpart);
            mean2_k<<<B_,          256, 0, stream>>>(mpart, avgh);
            avgp = avgh;
        }
        mv5_k   <<<dim3(5,B_), 256, 0, stream>>>(svin, avgp, Wfg_g, Wfg_h, Wog_g,
                                                 Wog_h, Wfgi_g, res5);
        comb_k  <<<B_, 256, 0, stream>>>(res5, b_fg, gbias, b_fgi, fhg, ogg, svg);
        // layer0: segs 0-2 from hin; layer1: segs 0-1 (seg2 written by gates_k, seg3 by gather)
        buildx_k<<<M_, (l==0 ? 192 : 128), 0, stream>>>(hin, X);
        // one GEMM: cols 0..1791 = gate pre-activations (no bias), 1792..2047 = fgih
        mgemm256_k<<<512, 512, 0, stream>>>(X, WT, pre, KBIG, KBIG, KBIG, NB2, 8);
        scorep_k<<<dim3(32,B_), 256, 0, stream>>>(pre + NB, svg, cin, part, NB2);
        newscs_k<<<B_, 256, 0, stream>>>(part, fhg, ogg, scin, scout, svout);
        gterm_k <<<dim3(7,B_), 256, 0, stream>>>(svout, Wg, gbias, gt);
        gates_k <<<M_/4, 256, 0, stream>>>(pre, gt, cin, scin, hout, cout,
                                           (l==0 ? X : (bf16*)nullptr), NB2);
        hin = hout; cin = cout;
        hout = (l==0) ? hhB : hhA;
        cout = (l==0) ? csB : csA;
        float* q;
        q = svin; svin = svout; svout = q;
        q = scin; scin = scout; scout = q;
    }
    mean1_k<<<dim3(B_,16), 256, 0, stream>>>(hin, mpart);
    mean2_k<<<B_,          256, 0, stream>>>(mpart, avgh);
    head_k <<<B_, 256, 0, stream>>>(avgh, svin, W1, b1, Wout, bout, (float*)d_out);
}

// Round 9
// 512.000 us; speedup vs baseline: 1.0577x; 1.0577x over previous
//
#include <hip/hip_runtime.h>
#include <stdint.h>
#include <math.h>

#define B_   32
#define S_   512
#define H_   256
#define M_   (B_*S_)     // 16384 tokens
#define KBIG 1024        // [hb|ha|hh|wv]
#define NB   1792        // 7*H
#define NB2  2048        // 7*H gates + 256 fgih rows (zero-padded K)
#define C_   5

typedef __bf16 bf16;
typedef __bf16 bf16x4 __attribute__((ext_vector_type(4)));
typedef __bf16 bf16x8 __attribute__((ext_vector_type(8)));
typedef float  floatx4 __attribute__((ext_vector_type(4)));

__device__ __forceinline__ float sigm(float x){ return 1.f/(1.f+expf(-x)); }

// async global->LDS, 16B per lane; LDS dest must be wave-uniform base + lane*16
__device__ __forceinline__ void gl16(const bf16* g, bf16* l){
    __builtin_amdgcn_global_load_lds(
        (const __attribute__((address_space(1))) unsigned int*)g,
        (__attribute__((address_space(3))) unsigned int*)l, 16, 0, 0);
}

// ---------- WT2: rows 0..1791 = [W_lr|W_c|W_x]; rows 1792..2047 = [0|Wfgi_h|0] ----------
__global__ void wcomb_k(const float* __restrict__ Wlr, const float* __restrict__ Wc,
                        const float* __restrict__ Wx, const float* __restrict__ Wfgi,
                        bf16* __restrict__ WT){
    int n = blockIdx.x;           // 0..2047
    int k4 = threadIdx.x * 4;     // 0..1020
    float4 v;
    if (n < NB){
        int g = n >> 8, h = n & 255;
        const float* src;
        if (k4 < 512)      src = Wlr + ((size_t)(g*256 + h))*512 + k4;
        else if (k4 < 768) src = Wc  + ((size_t)(g*256 + h))*256 + (k4 - 512);
        else               src = Wx  + ((size_t)(g*256 + h))*256 + (k4 - 768);
        v = *(const float4*)src;
    } else {
        int h = n - NB;
        if (k4 >= 512 && k4 < 768) v = *(const float4*)(Wfgi + (size_t)h*H_ + (k4 - 512));
        else { v.x=0.f; v.y=0.f; v.z=0.f; v.w=0.f; }
    }
    bf16 o[4] = {(bf16)v.x,(bf16)v.y,(bf16)v.z,(bf16)v.w};
    *(uint2*)&WT[(size_t)n*KBIG + k4] = *(uint2*)o;
}

// ---------- X[m, 768+h] = (bf16)embed[idx[m],h]  (seg-3 static across layers) ----------
__global__ void gather_k(const int* __restrict__ idx, const float* __restrict__ embed,
                         bf16* __restrict__ X){
    int i4 = (blockIdx.x*256 + threadIdx.x)*4;
    int m = i4 >> 8, h = i4 & 255;
    float4 v = *(const float4*)(embed + (size_t)idx[m]*H_ + h);
    bf16 o[4] = {(bf16)v.x,(bf16)v.y,(bf16)v.z,(bf16)v.w};
    *(uint2*)(X + (size_t)m*KBIG + 768 + h) = *(uint2*)o;
}

// ---------- two-stage mean over S ----------
__global__ void mean1_k(const float* __restrict__ x, float* __restrict__ part){
    int b = blockIdx.x, c = blockIdx.y, h = threadIdx.x;   // grid (B_,16)
    const float* p = x + ((size_t)b*S_ + c*32)*H_ + h;
    float s = 0.f;
    #pragma unroll 8
    for (int t=0;t<32;t++) s += p[(size_t)t*H_];
    part[((size_t)b*16 + c)*H_ + h] = s;
}
__global__ void mean2_k(const float* __restrict__ part, float* __restrict__ out){
    int b = blockIdx.x, h = threadIdx.x;
    float s = 0.f;
    #pragma unroll
    for (int c=0;c<16;c++) s += part[((size_t)b*16 + c)*H_ + h];
    out[b*H_ + h] = s * (1.f/512.f);
}

// ---------- X segs: 0=hb, 1=ha, 2=hh(bf16); XCD-chunked m for L2 locality of shifts ----------
__global__ void buildx_k(const float* __restrict__ hh, bf16* __restrict__ X){
    int bid = blockIdx.x;
    int m = (bid & 7)*(M_/8) + (bid >> 3);      // contiguous m-range per XCD
    int tid = threadIdx.x;
    int seg = tid >> 6, li = tid & 63;          // seg uniform per wave
    int s = m & (S_-1);
    int h0 = li*4;
    size_t base = (size_t)m*H_ + h0;
    bf16* xr = X + (size_t)m*KBIG + seg*H_ + h0;
    const float4 z = {0.f,0.f,0.f,0.f};
    float4 v;
    if (seg == 0){
        float4 a = (s>=1) ? *(const float4*)&hh[base - H_]   : z;
        float4 b = (s>=2) ? *(const float4*)&hh[base - 2*H_] : z;
        v.x=a.x+b.x; v.y=a.y+b.y; v.z=a.z+b.z; v.w=a.w+b.w;
    } else if (seg == 1){
        float4 a = (s<=S_-2) ? *(const float4*)&hh[base + H_]   : z;
        float4 b = (s<=S_-3) ? *(const float4*)&hh[base + 2*H_] : z;
        v.x=a.x+b.x; v.y=a.y+b.y; v.z=a.z+b.z; v.w=a.w+b.w;
    } else {
        v = *(const float4*)&hh[base];
    }
    bf16 o[4] = {(bf16)v.x,(bf16)v.y,(bf16)v.z,(bf16)v.w};
    *(uint2*)xr = *(uint2*)o;
}

// ---------- 5 small matvecs: res[b*5+j][h], float4 k-loop ----------
__global__ void mv5_k(const float* __restrict__ sv, const float* __restrict__ avg,
    const float* __restrict__ Wfg_g, const float* __restrict__ Wfg_h,
    const float* __restrict__ Wog_g, const float* __restrict__ Wog_h,
    const float* __restrict__ Wfgi_g, float* __restrict__ res){
    int j = blockIdx.x, b = blockIdx.y, h = threadIdx.x;   // grid (5,B_)
    const float* vec = (j==1 || j==3) ? avg + b*H_ : sv + b*H_;
    const float* W   = (j==0)?Wfg_g:(j==1)?Wfg_h:(j==2)?Wog_g:(j==3)?Wog_h:Wfgi_g;
    __shared__ float v[H_];
    v[h] = vec[h]; __syncthreads();
    const float* w = W + (size_t)h*H_;
    float d = 0.f;
    #pragma unroll 4
    for (int k=0;k<H_;k+=4){
        float4 wv4 = *(const float4*)&w[k];
        float4 vv4 = *(const float4*)&v[k];
        d += vv4.x*wv4.x + vv4.y*wv4.y + vv4.z*wv4.z + vv4.w*wv4.w;
    }
    res[((size_t)b*5 + j)*H_ + h] = d;
}

// ---------- 256x256 MFMA GEMM, 4-phase fine-interleaved pipeline (R3/R6 config: 81us) ----------
__device__ __forceinline__ void mmq(floatx4 (&acc)[8][4], bf16x8 (&af)[4][2], bf16x8 (&bfr)[2][2],
                                    int MH, int NH){
    #pragma unroll
    for (int mi2=0;mi2<4;mi2++)
        #pragma unroll
        for (int ni2=0;ni2<2;ni2++)
            #pragma unroll
            for (int kk=0;kk<2;kk++)
                acc[MH*4+mi2][NH*2+ni2] = __builtin_amdgcn_mfma_f32_16x16x32_bf16(
                    af[mi2][kk], bfr[ni2][kk], acc[MH*4+mi2][NH*2+ni2], 0, 0, 0);
}

__global__ __launch_bounds__(512, 2)
void mgemm256_k(const bf16* __restrict__ A, const bf16* __restrict__ BT,
                bf16* __restrict__ C, int Kdim, int lda, int ldb, int ldc, int nbx){
    __shared__ alignas(16) bf16 lsA[2][256*64];
    __shared__ alignas(16) bf16 lsB[2][256*64];
    const int tid  = threadIdx.x;
    const int lane = tid & 63;
    const int wave = tid >> 6;
    const int wm = wave >> 2;          // 0..1  (m half: rows wm*128..+127)
    const int wn = wave & 3;           // 0..3  (n quarter: cols wn*64..+63)
    const int lrow = lane & 15, quad = lane >> 4;

    // XCD-chunked swizzle (gridDim.x % 8 == 0 -> bijective)
    const int cpx = gridDim.x >> 3;
    const int w   = (blockIdx.x & 7)*cpx + (blockIdx.x >> 3);
    const int mb  = w / nbx, nb = w - mb*nbx;
    const int m0 = mb * 256, n0 = nb * 256;

    // staging: round r covers rows r*64 + (tid>>3), 8 swizzled cols per thread
    const int srow = tid >> 3;                         // 0..63
    const int scol = ((tid & 7) ^ (srow & 7)) * 8;     // pre-swizzled source col
    const bf16* Ab = A  + (size_t)(m0 + srow)*lda + scol;
    const bf16* Bb = BT + (size_t)(n0 + srow)*ldb + scol;
    const int NT = Kdim >> 6;

    floatx4 zero = {0.f,0.f,0.f,0.f};
    floatx4 acc[8][4];
    #pragma unroll
    for (int i=0;i<8;i++)
        #pragma unroll
        for (int j=0;j<4;j++) acc[i][j] = zero;
    bf16x8 af[4][2], bfrA[2][2], bfrB[2][2];

#define SA_(bu,r,kt) gl16(Ab + (size_t)(r)*64*lda + (size_t)(kt)*64, &lsA[bu][(r)*4096 + tid*8])
#define SB_(bu,r,kt) gl16(Bb + (size_t)(r)*64*ldb + (size_t)(kt)*64, &lsB[bu][(r)*4096 + tid*8])
#define RA_(bu,MH,mi2,kk) (*(const bf16x8*)&lsA[bu][(wm*128 + (MH)*64 + (mi2)*16 + lrow)*64 + ((((kk)*4+quad) ^ (lrow&7))*8)])
#define RB_(bu,NH,ni2,kk) (*(const bf16x8*)&lsB[bu][(wn*64  + (NH)*32 + (ni2)*16 + lrow)*64 + ((((kk)*4+quad) ^ (lrow&7))*8)])

    // prologue: tile 0 -> buf 0; drain B0-3,A0,A2 (needed by Q1), keep A1,A3 flying
    SB_(0,0,0); SB_(0,1,0); SB_(0,2,0); SB_(0,3,0);
    SA_(0,0,0); SA_(0,2,0); SA_(0,1,0); SA_(0,3,0);
    asm volatile("s_waitcnt vmcnt(2)" ::: "memory");
    __builtin_amdgcn_s_barrier();

    for (int kt = 0; kt < NT; ++kt){
        const int cur = kt & 1, nxt = cur ^ 1;
        const bool st = (kt + 1 < NT);
        const int k1 = kt + 1;

        // ---- Q1: (mh0, nh0) ---- reads A(MH0)+B(NH0); stages B0,B1
        #pragma unroll
        for (int mi2=0;mi2<4;mi2++){ af[mi2][0] = RA_(cur,0,mi2,0); af[mi2][1] = RA_(cur,0,mi2,1); }
        #pragma unroll
        for (int ni2=0;ni2<2;ni2++){ bfrA[ni2][0] = RB_(cur,0,ni2,0); bfrA[ni2][1] = RB_(cur,0,ni2,1); }
        if (st){ SB_(nxt,0,k1); SB_(nxt,1,k1); }
        __builtin_amdgcn_s_barrier();
        __builtin_amdgcn_s_setprio(1);
        mmq(acc, af, bfrA, 0, 0);
        __builtin_amdgcn_s_setprio(0);
        __builtin_amdgcn_s_barrier();

        // ---- Q2: (mh0, nh1) ---- reads B(NH1), reuse af; stages B2,B3
        #pragma unroll
        for (int ni2=0;ni2<2;ni2++){ bfrB[ni2][0] = RB_(cur,1,ni2,0); bfrB[ni2][1] = RB_(cur,1,ni2,1); }
        if (st){ SB_(nxt,2,k1); SB_(nxt,3,k1); }
        __builtin_amdgcn_s_barrier();
        __builtin_amdgcn_s_setprio(1);
        mmq(acc, af, bfrB, 0, 1);
        __builtin_amdgcn_s_setprio(0);
        if (st) asm volatile("s_waitcnt vmcnt(4)" ::: "memory");   // prev iter's A1,A3 landed
        else    asm volatile("s_waitcnt vmcnt(0)" ::: "memory");   // tail drain
        __builtin_amdgcn_s_barrier();

        // ---- Q3: (mh1, nh1) ---- reads A(MH1), reuse bfrB; stages A0,A2
        #pragma unroll
        for (int mi2=0;mi2<4;mi2++){ af[mi2][0] = RA_(cur,1,mi2,0); af[mi2][1] = RA_(cur,1,mi2,1); }
        if (st){ SA_(nxt,0,k1); SA_(nxt,2,k1); }
        __builtin_amdgcn_s_barrier();
        __builtin_amdgcn_s_setprio(1);
        mmq(acc, af, bfrB, 1, 1);
        __builtin_amdgcn_s_setprio(0);
        __builtin_amdgcn_s_barrier();

        // ---- Q4: (mh1, nh0) ---- no reads (af from Q3, bfrA from Q1); stages A1,A3
        if (st){ SA_(nxt,1,k1); SA_(nxt,3,k1); }
        __builtin_amdgcn_s_barrier();
        __builtin_amdgcn_s_setprio(1);
        mmq(acc, af, bfrA, 1, 0);
        __builtin_amdgcn_s_setprio(0);
        if (st) asm volatile("s_waitcnt vmcnt(2)" ::: "memory");   // B0-3,A0,A2 of next tile landed
        __builtin_amdgcn_s_barrier();
    }
#undef SA_
#undef SB_
#undef RA_
#undef RB_

    #pragma unroll
    for (int mi=0;mi<8;mi++)
        #pragma unroll
        for (int ni=0;ni<4;ni++){
            int row = m0 + wm*128 + mi*16 + quad*4;
            int col = n0 + wn*64  + ni*16 + lrow;
            #pragma unroll
            for (int r=0;r<4;r++)
                C[(size_t)(row+r)*ldc + col] = (bf16)acc[mi][ni][r];
        }
}

// ---------- fused score+partial; svg computed inline from res5 row 4 ----------
__global__ void scorep_k(const bf16* __restrict__ fgih, const float* __restrict__ res5,
                         const float* __restrict__ b_fgi,
                         const float* __restrict__ cs, float* __restrict__ part, int ldf){
    int chunk = blockIdx.x, b = blockIdx.y;                 // grid (32,B_)
    int tid = threadIdx.x, wave = tid >> 6, lane = tid & 63;
    __shared__ float acc4[4][256];
    int h0 = lane*4;
    float4 r4 = *(const float4*)&res5[((size_t)b*5 + 4)*H_ + h0];
    float4 bf = *(const float4*)&b_fgi[h0];
    float sw[4] = {r4.x+bf.x, r4.y+bf.y, r4.z+bf.z, r4.w+bf.w};
    float acc[4] = {0.f,0.f,0.f,0.f};
    for (int t=wave; t<16; t+=4){
        int m = b*S_ + chunk*16 + t;
        bf16x4 fv = *(const bf16x4*)&fgih[(size_t)m*ldf + h0];
        float e[4], loc = 0.f;
        #pragma unroll
        for (int j=0;j<4;j++){ e[j] = expf(sigm(sw[j] + (float)fv[j])); loc += e[j]; }
        #pragma unroll
        for (int off=32; off; off>>=1) loc += __shfl_xor(loc, off, 64);
        float inv = 1.f/loc;
        float4 cv = *(const float4*)&cs[(size_t)m*H_ + h0];
        acc[0] += e[0]*inv*cv.x; acc[1] += e[1]*inv*cv.y;
        acc[2] += e[2]*inv*cv.z; acc[3] += e[3]*inv*cv.w;
    }
    #pragma unroll
    for (int j=0;j<4;j++) acc4[wave][h0+j] = acc[j];
    __syncthreads();
    part[((size_t)b*32 + chunk)*H_ + tid] =
        acc4[0][tid] + acc4[1][tid] + acc4[2][tid] + acc4[3][tid];
}

// ---------- new_scs / new_sv; fhg/ogg computed inline from res5 (comb_k folded in) ----------
__global__ void newscs_k(const float* __restrict__ part, const float* __restrict__ res5,
                         const float* __restrict__ b_fg, const float* __restrict__ gbias,
                         const float* __restrict__ scs_in,
                         float* __restrict__ scs_out, float* __restrict__ sv_out){
    int b = blockIdx.x, h = threadIdx.x;
    __shared__ float r[256];
    float dot = 0.f;
    #pragma unroll 8
    for (int c=0;c<32;c++) dot += part[((size_t)b*32+c)*H_ + h];
    const float* rr = res5 + (size_t)b*5*H_;
    float fhg = sigm(rr[h] + rr[H_+h] + b_fg[h]);
    float ogg = sigm(rr[2*H_+h] + rr[3*H_+h] + gbias[5*H_+h]);  // gate_bias[5] per ref
    float e = expf(fhg);
    r[h] = e; __syncthreads();
    for (int off=128; off; off>>=1){ if (h<off) r[h] += r[h+off]; __syncthreads(); }
    float ns = (e / r[0]) * scs_in[b*H_+h] + dot;
    scs_out[b*H_+h] = ns;
    sv_out[b*H_+h]  = ogg * tanhf(ns);
}

// ---------- gt[b, g*256+h] = sum_k new_sv[b,k]*W_g[g,h,k] + gate_bias[g,h], float4 k-loop ----------
__global__ void gterm_k(const float* __restrict__ svn, const float* __restrict__ Wg,
                        const float* __restrict__ gbias, float* __restrict__ gt){
    int g = blockIdx.x, b = blockIdx.y, h = threadIdx.x;
    __shared__ float s[H_];
    s[h] = svn[b*H_+h]; __syncthreads();
    const float* w = Wg + ((size_t)g*H_ + h)*H_;
    float d = 0.f;
    #pragma unroll 4
    for (int k=0;k<H_;k+=4){
        float4 wv4 = *(const float4*)&w[k];
        float4 vv4 = *(const float4*)&s[k];
        d += vv4.x*wv4.x + vv4.y*wv4.y + vv4.z*wv4.z + vv4.w*wv4.w;
    }
    gt[(size_t)b*NB + g*H_ + h] = d + gbias[g*H_+h];
}

// ---------- joint softmax over 5H + state update; XCD-chunked m; writes next X seg-2 ----------
__global__ void gates_k(const bf16* __restrict__ pre, const float* __restrict__ gt,
                        const float* __restrict__ cs_in, const float* __restrict__ scs_in,
                        float* __restrict__ hh_out, float* __restrict__ cs_out,
                        bf16* __restrict__ Xn, int ldp){
    int tid = threadIdx.x, wave = tid >> 6, lane = tid & 63;
    int bid = blockIdx.x;
    int bid2 = (bid & 7)*(M_/32) + (bid >> 3);               // contiguous m-range per XCD
    int m = bid2*4 + wave;                                   // grid M_/4
    int b = m >> 9, s = m & (S_-1);
    const bf16* row = pre + (size_t)m*ldp;
    int h0 = lane*4;
    float pv[7][4];
    #pragma unroll
    for (int g=0; g<7; ++g){
        bf16x4 t = *(const bf16x4*)&row[g*H_ + h0];
        float4 gq = *(const float4*)&gt[(size_t)b*NB + g*H_ + h0];
        pv[g][0] = (float)t[0] + gq.x;
        pv[g][1] = (float)t[1] + gq.y;
        pv[g][2] = (float)t[2] + gq.z;
        pv[g][3] = (float)t[3] + gq.w;
    }
    float ex[5][4], og[4], u[4];
    float loc = 0.f;
    #pragma unroll
    for (int g=0; g<5; ++g)
        #pragma unroll
        for (int j=0;j<4;j++){ float e = expf(sigm(pv[g][j])); ex[g][j] = e; loc += e; }
    #pragma unroll
    for (int j=0;j<4;j++){ og[j] = sigm(pv[5][j]); u[j] = tanhf(pv[6][j]); }
    #pragma unroll
    for (int off=32; off; off>>=1) loc += __shfl_xor(loc, off, 64);
    float inv = 1.f / loc;

    size_t i0 = (size_t)m*H_ + h0;
    const float4 z = {0.f,0.f,0.f,0.f};
    float4 c0  = *(const float4*)&cs_in[i0];
    float4 cm1 = (s>=1)    ? *(const float4*)&cs_in[i0 - H_]   : z;
    float4 cm2 = (s>=2)    ? *(const float4*)&cs_in[i0 - 2*H_] : z;
    float4 cp1 = (s<=S_-2) ? *(const float4*)&cs_in[i0 + H_]   : z;
    float4 cp2 = (s<=S_-3) ? *(const float4*)&cs_in[i0 + 2*H_] : z;
    float4 sc  = *(const float4*)&scs_in[(size_t)b*H_ + h0];
    float4 nc4, nh4;
    #pragma unroll
    for (int j=0;j<4;j++){
        float cb = ((const float*)&cm1)[j] + ((const float*)&cm2)[j];
        float ca = ((const float*)&cp1)[j] + ((const float*)&cp2)[j];
        // gate order i,l,r,f,s: new_cs = l*cb + f*cs + r*ca + s*scs + i*u
        float nc = ex[1][j]*inv*cb + ex[3][j]*inv*((const float*)&c0)[j] + ex[2][j]*inv*ca
                 + ex[4][j]*inv*((const float*)&sc)[j] + ex[0][j]*inv*u[j];
        ((float*)&nc4)[j] = nc;
        ((float*)&nh4)[j] = og[j] * tanhf(nc);
    }
    *(float4*)&cs_out[i0] = nc4;
    *(float4*)&hh_out[i0] = nh4;
    if (Xn){
        bf16 o[4] = {(bf16)((float*)&nh4)[0], (bf16)((float*)&nh4)[1],
                     (bf16)((float*)&nh4)[2], (bf16)((float*)&nh4)[3]};
        *(uint2*)&Xn[(size_t)m*KBIG + 512 + h0] = *(uint2*)o;
    }
}

// ---------- output head (float32 out), float4 k-loops via LDS-staged inputs ----------
__global__ void head_k(const float* __restrict__ avgh, const float* __restrict__ sv,
                       const float* __restrict__ W1, const float* __restrict__ b1,
                       const float* __restrict__ Wout, const float* __restrict__ bout,
                       float* __restrict__ out){
    int b = blockIdx.x, t = threadIdx.x;
    __shared__ float sa[H_], ss[H_];
    __shared__ float conc[H_];
    __shared__ float fc[8];
    sa[t] = avgh[b*H_+t]; ss[t] = sv[b*H_+t];
    __syncthreads();
    const float* wr = W1 + (size_t)t*512;
    float d = b1[t];
    #pragma unroll 4
    for (int k=0;k<H_;k+=4){
        float4 w4 = *(const float4*)&wr[k];
        float4 a4 = *(const float4*)&sa[k];
        d += a4.x*w4.x + a4.y*w4.y + a4.z*w4.z + a4.w*w4.w;
    }
    #pragma unroll 4
    for (int k=0;k<H_;k+=4){
        float4 w4 = *(const float4*)&wr[256+k];
        float4 s4 = *(const float4*)&ss[k];
        d += s4.x*w4.x + s4.y*w4.y + s4.z*w4.z + s4.w*w4.w;
    }
    conc[t] = d;
    __syncthreads();
    if (t < C_){
        const float* wo = Wout + (size_t)t*H_;
        float s = bout[t];
        #pragma unroll 4
        for (int i=0;i<H_;i+=4){
            float4 w4 = *(const float4*)&wo[i];
            float4 c4 = *(const float4*)&conc[i];
            s += c4.x*w4.x + c4.y*w4.y + c4.z*w4.z + c4.w*w4.w;
        }
        fc[t] = s;
    }
    __syncthreads();
    if (t == 0){
        float mx = fc[0];
        for (int c=1;c<C_;c++) mx = fmaxf(mx, fc[c]);
        float se = 0.f;
        for (int c=0;c<C_;c++) se += expf(fc[c]-mx);
        float lse = mx + logf(se);
        for (int c=0;c<C_;c++) out[b*C_+c] = fc[c]-lse;
    }
    out[B_*C_ + b*H_ + t] = ss[t];
}

// ---------------- host ----------------
extern "C" void kernel_launch(void* const* d_in, const int* in_sizes, int n_in,
                              void* d_out, int out_size, void* d_ws, size_t ws_size,
                              hipStream_t stream){
    const int*   idx    = (const int*)d_in[0];
    const float* hh0    = (const float*)d_in[2];
    const float* cs0    = (const float*)d_in[3];
    const float* embed  = (const float*)d_in[4];
    const float* Wlr    = (const float*)d_in[5];
    const float* Wc     = (const float*)d_in[6];
    const float* Wx     = (const float*)d_in[7];
    const float* Wg     = (const float*)d_in[8];
    const float* gbias  = (const float*)d_in[9];
    const float* Wfg_g  = (const float*)d_in[10];
    const float* Wfg_h  = (const float*)d_in[11];
    const float* Wfgi_g = (const float*)d_in[12];
    const float* Wfgi_h = (const float*)d_in[13];
    const float* Wog_g  = (const float*)d_in[14];
    const float* Wog_h  = (const float*)d_in[15];
    const float* b_fg   = (const float*)d_in[16];
    const float* b_fgi  = (const float*)d_in[17];
    const float* W1     = (const float*)d_in[18];
    const float* b1     = (const float*)d_in[19];
    const float* Wout   = (const float*)d_in[20];
    const float* bout   = (const float*)d_in[21];

    uint8_t* p = (uint8_t*)d_ws;
    auto alloc = [&](size_t bytes)->void*{ void* r=(void*)p; p += (bytes + 255) & ~(size_t)255; return r; };
    bf16*  WT    = (bf16*)alloc((size_t)NB2*KBIG*2);   //  4.2 MB
    bf16*  X     = (bf16*)alloc((size_t)M_*KBIG*2);    // 33.6 MB
    bf16*  pre   = (bf16*)alloc((size_t)M_*NB2*2);     // 67.1 MB  (cols 1792.. = fgih)
    float* hhA = (float*)alloc((size_t)M_*H_*4);
    float* csA = (float*)alloc((size_t)M_*H_*4);
    float* hhB = (float*)alloc((size_t)M_*H_*4);
    float* csB = (float*)alloc((size_t)M_*H_*4);
    float* mpart= (float*)alloc((size_t)B_*16*H_*4);
    float* part = (float*)alloc((size_t)B_*32*H_*4);
    float* res5 = (float*)alloc((size_t)B_*5*H_*4);
    float* avgh = (float*)alloc(B_*H_*4);
    float* svP0 = (float*)alloc(B_*H_*4);
    float* svP1 = (float*)alloc(B_*H_*4);
    float* scP0 = (float*)alloc(B_*H_*4);
    float* scP1 = (float*)alloc(B_*H_*4);
    float* gt   = (float*)alloc((size_t)B_*NB*4);

    wcomb_k <<<NB2,         256, 0, stream>>>(Wlr, Wc, Wx, Wfgi_h, WT);
    gather_k<<<(M_*H_)/1024,256, 0, stream>>>(idx, embed, X);
    mean1_k <<<dim3(B_,16), 256, 0, stream>>>(hh0, mpart);
    mean2_k <<<B_,          256, 0, stream>>>(mpart, svP0);   // sv0 == avg_hh(layer0)
    mean1_k <<<dim3(B_,16), 256, 0, stream>>>(cs0, mpart);
    mean2_k <<<B_,          256, 0, stream>>>(mpart, scP0);

    const float *hin = hh0, *cin = cs0;
    float *hout = hhA, *cout = csA;
    float *svin = svP0, *scin = scP0, *svout = svP1, *scout = scP1;

    for (int l=0; l<2; ++l){
        const float* avgp;
        if (l == 0){
            avgp = svin;            // mean(hh0) == initial sv
        } else {
            mean1_k<<<dim3(B_,16), 256, 0, stream>>>(hin, mpart);
            mean2_k<<<B_,          256, 0, stream>>>(mpart, avgh);
            avgp = avgh;
        }
        mv5_k   <<<dim3(5,B_), 256, 0, stream>>>(svin, avgp, Wfg_g, Wfg_h, Wog_g,
                                                 Wog_h, Wfgi_g, res5);
        // layer0: segs 0-2 from hin; layer1: segs 0-1 (seg2 written by gates_k, seg3 by gather)
        buildx_k<<<M_, (l==0 ? 192 : 128), 0, stream>>>(hin, X);
        // one GEMM: cols 0..1791 = gate pre-activations (no bias), 1792..2047 = fgih
        mgemm256_k<<<512, 512, 0, stream>>>(X, WT, pre, KBIG, KBIG, KBIG, NB2, 8);
        scorep_k<<<dim3(32,B_), 256, 0, stream>>>(pre + NB, res5, b_fgi, cin, part, NB2);
        newscs_k<<<B_, 256, 0, stream>>>(part, res5, b_fg, gbias, scin, scout, svout);
        gterm_k <<<dim3(7,B_), 256, 0, stream>>>(svout, Wg, gbias, gt);
        gates_k <<<M_/4, 256, 0, stream>>>(pre, gt, cin, scin, hout, cout,
                                           (l==0 ? X : (bf16*)nullptr), NB2);
        hin = hout; cin = cout;
        hout = (l==0) ? hhB : hhA;
        cout = (l==0) ? csB : csA;
        float* q;
        q = svin; svin = svout; svout = q;
        q = scin; scin = scout; scout = q;
    }
    mean1_k<<<dim3(B_,16), 256, 0, stream>>>(hin, mpart);
    mean2_k<<<B_,          256, 0, stream>>>(mpart, avgh);
    head_k <<<B_, 256, 0, stream>>>(avgh, svin, W1, b1, Wout, bout, (float*)d_out);
}

// Round 10
// 490.847 us; speedup vs baseline: 1.1033x; 1.0431x over previous
//
#include <hip/hip_runtime.h>
#include <stdint.h>
#include <math.h>

#define B_   32
#define S_   512
#define H_   256
#define M_   (B_*S_)     // 16384 tokens
#define KBIG 1024        // [hb|ha|hh|wv]
#define NB   1792        // 7*H
#define NB2  2048        // 7*H gates + 256 fgih rows (zero-padded K)
#define C_   5

typedef __bf16 bf16;
typedef __bf16 bf16x4 __attribute__((ext_vector_type(4)));
typedef __bf16 bf16x8 __attribute__((ext_vector_type(8)));
typedef float  floatx4 __attribute__((ext_vector_type(4)));

__device__ __forceinline__ float sigm(float x){ return 1.f/(1.f+expf(-x)); }
// fast transcendentals (v_exp-based): used in the M_-scale kernels only
__device__ __forceinline__ float fsigm(float x){ return 1.f/(1.f+__expf(-x)); }
__device__ __forceinline__ float ftanh(float x){ return 1.f - 2.f/(1.f+__expf(2.f*x)); }

// async global->LDS, 16B per lane; LDS dest must be wave-uniform base + lane*16
__device__ __forceinline__ void gl16(const bf16* g, bf16* l){
    __builtin_amdgcn_global_load_lds(
        (const __attribute__((address_space(1))) unsigned int*)g,
        (__attribute__((address_space(3))) unsigned int*)l, 16, 0, 0);
}

// ---------- WT2: rows 0..1791 = [W_lr|W_c|W_x]; rows 1792..2047 = [0|Wfgi_h|0] ----------
__global__ void wcomb_k(const float* __restrict__ Wlr, const float* __restrict__ Wc,
                        const float* __restrict__ Wx, const float* __restrict__ Wfgi,
                        bf16* __restrict__ WT){
    int n = blockIdx.x;           // 0..2047
    int k4 = threadIdx.x * 4;     // 0..1020
    float4 v;
    if (n < NB){
        int g = n >> 8, h = n & 255;
        const float* src;
        if (k4 < 512)      src = Wlr + ((size_t)(g*256 + h))*512 + k4;
        else if (k4 < 768) src = Wc  + ((size_t)(g*256 + h))*256 + (k4 - 512);
        else               src = Wx  + ((size_t)(g*256 + h))*256 + (k4 - 768);
        v = *(const float4*)src;
    } else {
        int h = n - NB;
        if (k4 >= 512 && k4 < 768) v = *(const float4*)(Wfgi + (size_t)h*H_ + (k4 - 512));
        else { v.x=0.f; v.y=0.f; v.z=0.f; v.w=0.f; }
    }
    bf16 o[4] = {(bf16)v.x,(bf16)v.y,(bf16)v.z,(bf16)v.w};
    *(uint2*)&WT[(size_t)n*KBIG + k4] = *(uint2*)o;
}

// ---------- X[m, 768+h] = (bf16)embed[idx[m],h]  (seg-3 static across layers) ----------
__global__ void gather_k(const int* __restrict__ idx, const float* __restrict__ embed,
                         bf16* __restrict__ X){
    int i4 = (blockIdx.x*256 + threadIdx.x)*4;
    int m = i4 >> 8, h = i4 & 255;
    float4 v = *(const float4*)(embed + (size_t)idx[m]*H_ + h);
    bf16 o[4] = {(bf16)v.x,(bf16)v.y,(bf16)v.z,(bf16)v.w};
    *(uint2*)(X + (size_t)m*KBIG + 768 + h) = *(uint2*)o;
}

// ---------- two-stage mean over S ----------
__global__ void mean1_k(const float* __restrict__ x, float* __restrict__ part){
    int b = blockIdx.x, c = blockIdx.y, h = threadIdx.x;   // grid (B_,16)
    const float* p = x + ((size_t)b*S_ + c*32)*H_ + h;
    float s = 0.f;
    #pragma unroll 8
    for (int t=0;t<32;t++) s += p[(size_t)t*H_];
    part[((size_t)b*16 + c)*H_ + h] = s;
}
__global__ void mean2_k(const float* __restrict__ part, float* __restrict__ out){
    int b = blockIdx.x, h = threadIdx.x;
    float s = 0.f;
    #pragma unroll
    for (int c=0;c<16;c++) s += part[((size_t)b*16 + c)*H_ + h];
    out[b*H_ + h] = s * (1.f/512.f);
}

// ---------- X segs: 0=hb, 1=ha, 2=hh(bf16); XCD-chunked m for L2 locality of shifts ----------
__global__ void buildx_k(const float* __restrict__ hh, bf16* __restrict__ X){
    int bid = blockIdx.x;
    int m = (bid & 7)*(M_/8) + (bid >> 3);      // contiguous m-range per XCD
    int tid = threadIdx.x;
    int seg = tid >> 6, li = tid & 63;          // seg uniform per wave
    int s = m & (S_-1);
    int h0 = li*4;
    size_t base = (size_t)m*H_ + h0;
    bf16* xr = X + (size_t)m*KBIG + seg*H_ + h0;
    const float4 z = {0.f,0.f,0.f,0.f};
    float4 v;
    if (seg == 0){
        float4 a = (s>=1) ? *(const float4*)&hh[base - H_]   : z;
        float4 b = (s>=2) ? *(const float4*)&hh[base - 2*H_] : z;
        v.x=a.x+b.x; v.y=a.y+b.y; v.z=a.z+b.z; v.w=a.w+b.w;
    } else if (seg == 1){
        float4 a = (s<=S_-2) ? *(const float4*)&hh[base + H_]   : z;
        float4 b = (s<=S_-3) ? *(const float4*)&hh[base + 2*H_] : z;
        v.x=a.x+b.x; v.y=a.y+b.y; v.z=a.z+b.z; v.w=a.w+b.w;
    } else {
        v = *(const float4*)&hh[base];
    }
    bf16 o[4] = {(bf16)v.x,(bf16)v.y,(bf16)v.z,(bf16)v.w};
    *(uint2*)xr = *(uint2*)o;
}

// ---------- 5 small matvecs: res[b*5+j][h], float4 k-loop ----------
__global__ void mv5_k(const float* __restrict__ sv, const float* __restrict__ avg,
    const float* __restrict__ Wfg_g, const float* __restrict__ Wfg_h,
    const float* __restrict__ Wog_g, const float* __restrict__ Wog_h,
    const float* __restrict__ Wfgi_g, float* __restrict__ res){
    int j = blockIdx.x, b = blockIdx.y, h = threadIdx.x;   // grid (5,B_)
    const float* vec = (j==1 || j==3) ? avg + b*H_ : sv + b*H_;
    const float* W   = (j==0)?Wfg_g:(j==1)?Wfg_h:(j==2)?Wog_g:(j==3)?Wog_h:Wfgi_g;
    __shared__ float v[H_];
    v[h] = vec[h]; __syncthreads();
    const float* w = W + (size_t)h*H_;
    float d = 0.f;
    #pragma unroll 4
    for (int k=0;k<H_;k+=4){
        float4 wv4 = *(const float4*)&w[k];
        float4 vv4 = *(const float4*)&v[k];
        d += vv4.x*wv4.x + vv4.y*wv4.y + vv4.z*wv4.z + vv4.w*wv4.w;
    }
    res[((size_t)b*5 + j)*H_ + h] = d;
}

// ---------- 256x256 MFMA GEMM, 4-phase fine-interleaved pipeline (R3/R6 config: 81us) ----------
__device__ __forceinline__ void mmq(floatx4 (&acc)[8][4], bf16x8 (&af)[4][2], bf16x8 (&bfr)[2][2],
                                    int MH, int NH){
    #pragma unroll
    for (int mi2=0;mi2<4;mi2++)
        #pragma unroll
        for (int ni2=0;ni2<2;ni2++)
            #pragma unroll
            for (int kk=0;kk<2;kk++)
                acc[MH*4+mi2][NH*2+ni2] = __builtin_amdgcn_mfma_f32_16x16x32_bf16(
                    af[mi2][kk], bfr[ni2][kk], acc[MH*4+mi2][NH*2+ni2], 0, 0, 0);
}

__global__ __launch_bounds__(512, 2)
void mgemm256_k(const bf16* __restrict__ A, const bf16* __restrict__ BT,
                bf16* __restrict__ C, int Kdim, int lda, int ldb, int ldc, int nbx){
    __shared__ alignas(16) bf16 lsA[2][256*64];
    __shared__ alignas(16) bf16 lsB[2][256*64];
    const int tid  = threadIdx.x;
    const int lane = tid & 63;
    const int wave = tid >> 6;
    const int wm = wave >> 2;          // 0..1  (m half: rows wm*128..+127)
    const int wn = wave & 3;           // 0..3  (n quarter: cols wn*64..+63)
    const int lrow = lane & 15, quad = lane >> 4;

    // XCD-chunked swizzle (gridDim.x % 8 == 0 -> bijective)
    const int cpx = gridDim.x >> 3;
    const int w   = (blockIdx.x & 7)*cpx + (blockIdx.x >> 3);
    const int mb  = w / nbx, nb = w - mb*nbx;
    const int m0 = mb * 256, n0 = nb * 256;

    // staging: round r covers rows r*64 + (tid>>3), 8 swizzled cols per thread
    const int srow = tid >> 3;                         // 0..63
    const int scol = ((tid & 7) ^ (srow & 7)) * 8;     // pre-swizzled source col
    const bf16* Ab = A  + (size_t)(m0 + srow)*lda + scol;
    const bf16* Bb = BT + (size_t)(n0 + srow)*ldb + scol;
    const int NT = Kdim >> 6;

    floatx4 zero = {0.f,0.f,0.f,0.f};
    floatx4 acc[8][4];
    #pragma unroll
    for (int i=0;i<8;i++)
        #pragma unroll
        for (int j=0;j<4;j++) acc[i][j] = zero;
    bf16x8 af[4][2], bfrA[2][2], bfrB[2][2];

#define SA_(bu,r,kt) gl16(Ab + (size_t)(r)*64*lda + (size_t)(kt)*64, &lsA[bu][(r)*4096 + tid*8])
#define SB_(bu,r,kt) gl16(Bb + (size_t)(r)*64*ldb + (size_t)(kt)*64, &lsB[bu][(r)*4096 + tid*8])
#define RA_(bu,MH,mi2,kk) (*(const bf16x8*)&lsA[bu][(wm*128 + (MH)*64 + (mi2)*16 + lrow)*64 + ((((kk)*4+quad) ^ (lrow&7))*8)])
#define RB_(bu,NH,ni2,kk) (*(const bf16x8*)&lsB[bu][(wn*64  + (NH)*32 + (ni2)*16 + lrow)*64 + ((((kk)*4+quad) ^ (lrow&7))*8)])

    // prologue: tile 0 -> buf 0; drain B0-3,A0,A2 (needed by Q1), keep A1,A3 flying
    SB_(0,0,0); SB_(0,1,0); SB_(0,2,0); SB_(0,3,0);
    SA_(0,0,0); SA_(0,2,0); SA_(0,1,0); SA_(0,3,0);
    asm volatile("s_waitcnt vmcnt(2)" ::: "memory");
    __builtin_amdgcn_s_barrier();

    for (int kt = 0; kt < NT; ++kt){
        const int cur = kt & 1, nxt = cur ^ 1;
        const bool st = (kt + 1 < NT);
        const int k1 = kt + 1;

        // ---- Q1: (mh0, nh0) ---- reads A(MH0)+B(NH0); stages B0,B1
        #pragma unroll
        for (int mi2=0;mi2<4;mi2++){ af[mi2][0] = RA_(cur,0,mi2,0); af[mi2][1] = RA_(cur,0,mi2,1); }
        #pragma unroll
        for (int ni2=0;ni2<2;ni2++){ bfrA[ni2][0] = RB_(cur,0,ni2,0); bfrA[ni2][1] = RB_(cur,0,ni2,1); }
        if (st){ SB_(nxt,0,k1); SB_(nxt,1,k1); }
        __builtin_amdgcn_s_barrier();
        __builtin_amdgcn_s_setprio(1);
        mmq(acc, af, bfrA, 0, 0);
        __builtin_amdgcn_s_setprio(0);
        __builtin_amdgcn_s_barrier();

        // ---- Q2: (mh0, nh1) ---- reads B(NH1), reuse af; stages B2,B3
        #pragma unroll
        for (int ni2=0;ni2<2;ni2++){ bfrB[ni2][0] = RB_(cur,1,ni2,0); bfrB[ni2][1] = RB_(cur,1,ni2,1); }
        if (st){ SB_(nxt,2,k1); SB_(nxt,3,k1); }
        __builtin_amdgcn_s_barrier();
        __builtin_amdgcn_s_setprio(1);
        mmq(acc, af, bfrB, 0, 1);
        __builtin_amdgcn_s_setprio(0);
        if (st) asm volatile("s_waitcnt vmcnt(4)" ::: "memory");   // prev iter's A1,A3 landed
        else    asm volatile("s_waitcnt vmcnt(0)" ::: "memory");   // tail drain
        __builtin_amdgcn_s_barrier();

        // ---- Q3: (mh1, nh1) ---- reads A(MH1), reuse bfrB; stages A0,A2
        #pragma unroll
        for (int mi2=0;mi2<4;mi2++){ af[mi2][0] = RA_(cur,1,mi2,0); af[mi2][1] = RA_(cur,1,mi2,1); }
        if (st){ SA_(nxt,0,k1); SA_(nxt,2,k1); }
        __builtin_amdgcn_s_barrier();
        __builtin_amdgcn_s_setprio(1);
        mmq(acc, af, bfrB, 1, 1);
        __builtin_amdgcn_s_setprio(0);
        __builtin_amdgcn_s_barrier();

        // ---- Q4: (mh1, nh0) ---- no reads (af from Q3, bfrA from Q1); stages A1,A3
        if (st){ SA_(nxt,1,k1); SA_(nxt,3,k1); }
        __builtin_amdgcn_s_barrier();
        __builtin_amdgcn_s_setprio(1);
        mmq(acc, af, bfrA, 1, 0);
        __builtin_amdgcn_s_setprio(0);
        if (st) asm volatile("s_waitcnt vmcnt(2)" ::: "memory");   // B0-3,A0,A2 of next tile landed
        __builtin_amdgcn_s_barrier();
    }
#undef SA_
#undef SB_
#undef RA_
#undef RB_

    #pragma unroll
    for (int mi=0;mi<8;mi++)
        #pragma unroll
        for (int ni=0;ni<4;ni++){
            int row = m0 + wm*128 + mi*16 + quad*4;
            int col = n0 + wn*64  + ni*16 + lrow;
            #pragma unroll
            for (int r=0;r<4;r++)
                C[(size_t)(row+r)*ldc + col] = (bf16)acc[mi][ni][r];
        }
}

// ---------- fused score+partial; svg inline from res5 row 4; fast transcendentals ----------
__global__ void scorep_k(const bf16* __restrict__ fgih, const float* __restrict__ res5,
                         const float* __restrict__ b_fgi,
                         const float* __restrict__ cs, float* __restrict__ part, int ldf){
    int chunk = blockIdx.x, b = blockIdx.y;                 // grid (32,B_)
    int tid = threadIdx.x, wave = tid >> 6, lane = tid & 63;
    __shared__ float acc4[4][256];
    int h0 = lane*4;
    float4 r4 = *(const float4*)&res5[((size_t)b*5 + 4)*H_ + h0];
    float4 bf = *(const float4*)&b_fgi[h0];
    float sw[4] = {r4.x+bf.x, r4.y+bf.y, r4.z+bf.z, r4.w+bf.w};
    float acc[4] = {0.f,0.f,0.f,0.f};
    for (int t=wave; t<16; t+=4){
        int m = b*S_ + chunk*16 + t;
        bf16x4 fv = *(const bf16x4*)&fgih[(size_t)m*ldf + h0];
        float e[4], loc = 0.f;
        #pragma unroll
        for (int j=0;j<4;j++){ e[j] = __expf(fsigm(sw[j] + (float)fv[j])); loc += e[j]; }
        #pragma unroll
        for (int off=32; off; off>>=1) loc += __shfl_xor(loc, off, 64);
        float inv = 1.f/loc;
        float4 cv = *(const float4*)&cs[(size_t)m*H_ + h0];
        acc[0] += e[0]*inv*cv.x; acc[1] += e[1]*inv*cv.y;
        acc[2] += e[2]*inv*cv.z; acc[3] += e[3]*inv*cv.w;
    }
    #pragma unroll
    for (int j=0;j<4;j++) acc4[wave][h0+j] = acc[j];
    __syncthreads();
    part[((size_t)b*32 + chunk)*H_ + tid] =
        acc4[0][tid] + acc4[1][tid] + acc4[2][tid] + acc4[3][tid];
}

// ---------- fused newscs+gterm: grid (7,B_); every block computes ns/sv (cheap, redundant),
// ---------- g==0 writes scs/sv; all blocks compute their gate's gt from LDS sv ----------
__global__ void nsg_k(const float* __restrict__ part, const float* __restrict__ res5,
                      const float* __restrict__ b_fg, const float* __restrict__ gbias,
                      const float* __restrict__ scs_in, const float* __restrict__ Wg,
                      float* __restrict__ scs_out, float* __restrict__ sv_out,
                      float* __restrict__ gt){
    int g = blockIdx.x, b = blockIdx.y, h = threadIdx.x;   // grid (7,B_)
    __shared__ float r[256];
    __shared__ float s[256];
    float dot = 0.f;
    #pragma unroll 8
    for (int c=0;c<32;c++) dot += part[((size_t)b*32+c)*H_ + h];
    const float* rr = res5 + (size_t)b*5*H_;
    float fhg = fsigm(rr[h] + rr[H_+h] + b_fg[h]);
    float ogg = fsigm(rr[2*H_+h] + rr[3*H_+h] + gbias[5*H_+h]);  // gate_bias[5] per ref
    float e = __expf(fhg);
    r[h] = e; __syncthreads();
    for (int off=128; off; off>>=1){ if (h<off) r[h] += r[h+off]; __syncthreads(); }
    float ns = (e / r[0]) * scs_in[b*H_+h] + dot;
    float sv = ogg * ftanh(ns);
    if (g == 0){ scs_out[b*H_+h] = ns; sv_out[b*H_+h] = sv; }
    s[h] = sv; __syncthreads();
    const float* w = Wg + ((size_t)g*H_ + h)*H_;
    float d = 0.f;
    #pragma unroll 4
    for (int k=0;k<H_;k+=4){
        float4 w4 = *(const float4*)&w[k];
        float4 s4 = *(const float4*)&s[k];
        d += s4.x*w4.x + s4.y*w4.y + s4.z*w4.z + s4.w*w4.w;
    }
    gt[(size_t)b*NB + g*H_ + h] = d + gbias[g*H_+h];
}

// ---------- joint softmax over 5H + state update; fast transcendentals; XCD-chunked m ----------
__global__ void gates_k(const bf16* __restrict__ pre, const float* __restrict__ gt,
                        const float* __restrict__ cs_in, const float* __restrict__ scs_in,
                        float* __restrict__ hh_out, float* __restrict__ cs_out,
                        bf16* __restrict__ Xn, int ldp){
    int tid = threadIdx.x, wave = tid >> 6, lane = tid & 63;
    int bid = blockIdx.x;
    int bid2 = (bid & 7)*(M_/32) + (bid >> 3);               // contiguous m-range per XCD
    int m = bid2*4 + wave;                                   // grid M_/4
    int b = m >> 9, s = m & (S_-1);
    const bf16* row = pre + (size_t)m*ldp;
    int h0 = lane*4;
    float pv[7][4];
    #pragma unroll
    for (int g=0; g<7; ++g){
        bf16x4 t = *(const bf16x4*)&row[g*H_ + h0];
        float4 gq = *(const float4*)&gt[(size_t)b*NB + g*H_ + h0];
        pv[g][0] = (float)t[0] + gq.x;
        pv[g][1] = (float)t[1] + gq.y;
        pv[g][2] = (float)t[2] + gq.z;
        pv[g][3] = (float)t[3] + gq.w;
    }
    float ex[5][4], og[4], u[4];
    float loc = 0.f;
    #pragma unroll
    for (int g=0; g<5; ++g)
        #pragma unroll
        for (int j=0;j<4;j++){ float e = __expf(fsigm(pv[g][j])); ex[g][j] = e; loc += e; }
    #pragma unroll
    for (int j=0;j<4;j++){ og[j] = fsigm(pv[5][j]); u[j] = ftanh(pv[6][j]); }
    #pragma unroll
    for (int off=32; off; off>>=1) loc += __shfl_xor(loc, off, 64);
    float inv = 1.f / loc;

    size_t i0 = (size_t)m*H_ + h0;
    const float4 z = {0.f,0.f,0.f,0.f};
    float4 c0  = *(const float4*)&cs_in[i0];
    float4 cm1 = (s>=1)    ? *(const float4*)&cs_in[i0 - H_]   : z;
    float4 cm2 = (s>=2)    ? *(const float4*)&cs_in[i0 - 2*H_] : z;
    float4 cp1 = (s<=S_-2) ? *(const float4*)&cs_in[i0 + H_]   : z;
    float4 cp2 = (s<=S_-3) ? *(const float4*)&cs_in[i0 + 2*H_] : z;
    float4 sc  = *(const float4*)&scs_in[(size_t)b*H_ + h0];
    float4 nc4, nh4;
    #pragma unroll
    for (int j=0;j<4;j++){
        float cb = ((const float*)&cm1)[j] + ((const float*)&cm2)[j];
        float ca = ((const float*)&cp1)[j] + ((const float*)&cp2)[j];
        // gate order i,l,r,f,s: new_cs = l*cb + f*cs + r*ca + s*scs + i*u
        float nc = ex[1][j]*inv*cb + ex[3][j]*inv*((const float*)&c0)[j] + ex[2][j]*inv*ca
                 + ex[4][j]*inv*((const float*)&sc)[j] + ex[0][j]*inv*u[j];
        ((float*)&nc4)[j] = nc;
        ((float*)&nh4)[j] = og[j] * ftanh(nc);
    }
    *(float4*)&cs_out[i0] = nc4;
    *(float4*)&hh_out[i0] = nh4;
    if (Xn){
        bf16 o[4] = {(bf16)((float*)&nh4)[0], (bf16)((float*)&nh4)[1],
                     (bf16)((float*)&nh4)[2], (bf16)((float*)&nh4)[3]};
        *(uint2*)&Xn[(size_t)m*KBIG + 512 + h0] = *(uint2*)o;
    }
}

// ---------- output head (float32 out), float4 k-loops via LDS-staged inputs; precise math ----------
__global__ void head_k(const float* __restrict__ avgh, const float* __restrict__ sv,
                       const float* __restrict__ W1, const float* __restrict__ b1,
                       const float* __restrict__ Wout, const float* __restrict__ bout,
                       float* __restrict__ out){
    int b = blockIdx.x, t = threadIdx.x;
    __shared__ float sa[H_], ss[H_];
    __shared__ float conc[H_];
    __shared__ float fc[8];
    sa[t] = avgh[b*H_+t]; ss[t] = sv[b*H_+t];
    __syncthreads();
    const float* wr = W1 + (size_t)t*512;
    float d = b1[t];
    #pragma unroll 4
    for (int k=0;k<H_;k+=4){
        float4 w4 = *(const float4*)&wr[k];
        float4 a4 = *(const float4*)&sa[k];
        d += a4.x*w4.x + a4.y*w4.y + a4.z*w4.z + a4.w*w4.w;
    }
    #pragma unroll 4
    for (int k=0;k<H_;k+=4){
        float4 w4 = *(const float4*)&wr[256+k];
        float4 s4 = *(const float4*)&ss[k];
        d += s4.x*w4.x + s4.y*w4.y + s4.z*w4.z + s4.w*w4.w;
    }
    conc[t] = d;
    __syncthreads();
    if (t < C_){
        const float* wo = Wout + (size_t)t*H_;
        float s = bout[t];
        #pragma unroll 4
        for (int i=0;i<H_;i+=4){
            float4 w4 = *(const float4*)&wo[i];
            float4 c4 = *(const float4*)&conc[i];
            s += c4.x*w4.x + c4.y*w4.y + c4.z*w4.z + c4.w*w4.w;
        }
        fc[t] = s;
    }
    __syncthreads();
    if (t == 0){
        float mx = fc[0];
        for (int c=1;c<C_;c++) mx = fmaxf(mx, fc[c]);
        float se = 0.f;
        for (int c=0;c<C_;c++) se += expf(fc[c]-mx);
        float lse = mx + logf(se);
        for (int c=0;c<C_;c++) out[b*C_+c] = fc[c]-lse;
    }
    out[B_*C_ + b*H_ + t] = ss[t];
}

// ---------------- host ----------------
extern "C" void kernel_launch(void* const* d_in, const int* in_sizes, int n_in,
                              void* d_out, int out_size, void* d_ws, size_t ws_size,
                              hipStream_t stream){
    const int*   idx    = (const int*)d_in[0];
    const float* hh0    = (const float*)d_in[2];
    const float* cs0    = (const float*)d_in[3];
    const float* embed  = (const float*)d_in[4];
    const float* Wlr    = (const float*)d_in[5];
    const float* Wc     = (const float*)d_in[6];
    const float* Wx     = (const float*)d_in[7];
    const float* Wg     = (const float*)d_in[8];
    const float* gbias  = (const float*)d_in[9];
    const float* Wfg_g  = (const float*)d_in[10];
    const float* Wfg_h  = (const float*)d_in[11];
    const float* Wfgi_g = (const float*)d_in[12];
    const float* Wfgi_h = (const float*)d_in[13];
    const float* Wog_g  = (const float*)d_in[14];
    const float* Wog_h  = (const float*)d_in[15];
    const float* b_fg   = (const float*)d_in[16];
    const float* b_fgi  = (const float*)d_in[17];
    const float* W1     = (const float*)d_in[18];
    const float* b1     = (const float*)d_in[19];
    const float* Wout   = (const float*)d_in[20];
    const float* bout   = (const float*)d_in[21];

    uint8_t* p = (uint8_t*)d_ws;
    auto alloc = [&](size_t bytes)->void*{ void* r=(void*)p; p += (bytes + 255) & ~(size_t)255; return r; };
    bf16*  WT    = (bf16*)alloc((size_t)NB2*KBIG*2);   //  4.2 MB
    bf16*  X     = (bf16*)alloc((size_t)M_*KBIG*2);    // 33.6 MB
    bf16*  pre   = (bf16*)alloc((size_t)M_*NB2*2);     // 67.1 MB  (cols 1792.. = fgih)
    float* hhA = (float*)alloc((size_t)M_*H_*4);
    float* csA = (float*)alloc((size_t)M_*H_*4);
    float* hhB = (float*)alloc((size_t)M_*H_*4);
    float* csB = (float*)alloc((size_t)M_*H_*4);
    float* mpart= (float*)alloc((size_t)B_*16*H_*4);
    float* part = (float*)alloc((size_t)B_*32*H_*4);
    float* res5 = (float*)alloc((size_t)B_*5*H_*4);
    float* avgh = (float*)alloc(B_*H_*4);
    float* svP0 = (float*)alloc(B_*H_*4);
    float* svP1 = (float*)alloc(B_*H_*4);
    float* scP0 = (float*)alloc(B_*H_*4);
    float* scP1 = (float*)alloc(B_*H_*4);
    float* gt   = (float*)alloc((size_t)B_*NB*4);

    wcomb_k <<<NB2,         256, 0, stream>>>(Wlr, Wc, Wx, Wfgi_h, WT);
    gather_k<<<(M_*H_)/1024,256, 0, stream>>>(idx, embed, X);
    mean1_k <<<dim3(B_,16), 256, 0, stream>>>(hh0, mpart);
    mean2_k <<<B_,          256, 0, stream>>>(mpart, svP0);   // sv0 == avg_hh(layer0)
    mean1_k <<<dim3(B_,16), 256, 0, stream>>>(cs0, mpart);
    mean2_k <<<B_,          256, 0, stream>>>(mpart, scP0);

    const float *hin = hh0, *cin = cs0;
    float *hout = hhA, *cout = csA;
    float *svin = svP0, *scin = scP0, *svout = svP1, *scout = scP1;

    for (int l=0; l<2; ++l){
        const float* avgp;
        if (l == 0){
            avgp = svin;            // mean(hh0) == initial sv
        } else {
            mean1_k<<<dim3(B_,16), 256, 0, stream>>>(hin, mpart);
            mean2_k<<<B_,          256, 0, stream>>>(mpart, avgh);
            avgp = avgh;
        }
        mv5_k   <<<dim3(5,B_), 256, 0, stream>>>(svin, avgp, Wfg_g, Wfg_h, Wog_g,
                                                 Wog_h, Wfgi_g, res5);
        // layer0: segs 0-2 from hin; layer1: segs 0-1 (seg2 written by gates_k, seg3 by gather)
        buildx_k<<<M_, (l==0 ? 192 : 128), 0, stream>>>(hin, X);
        // one GEMM: cols 0..1791 = gate pre-activations (no bias), 1792..2047 = fgih
        mgemm256_k<<<512, 512, 0, stream>>>(X, WT, pre, KBIG, KBIG, KBIG, NB2, 8);
        scorep_k<<<dim3(32,B_), 256, 0, stream>>>(pre + NB, res5, b_fgi, cin, part, NB2);
        nsg_k   <<<dim3(7,B_), 256, 0, stream>>>(part, res5, b_fg, gbias, scin, Wg,
                                                 scout, svout, gt);
        gates_k <<<M_/4, 256, 0, stream>>>(pre, gt, cin, scin, hout, cout,
                                           (l==0 ? X : (bf16*)nullptr), NB2);
        hin = hout; cin = cout;
        hout = (l==0) ? hhB : hhA;
        cout = (l==0) ? csB : csA;
        float* q;
        q = svin; svin = svout; svout = q;
        q = scin; scin = scout; scout = q;
    }
    mean1_k<<<dim3(B_,16), 256, 0, stream>>>(hin, mpart);
    mean2_k<<<B_,          256, 0, stream>>>(mpart, avgh);
    head_k <<<B_, 256, 0, stream>>>(avgh, svin, W1, b1, Wout, bout, (float*)d_out);
}